// Round 16
// baseline (118.468 us; speedup 1.0000x reference)
//
#include <hip/hip_runtime.h>
#include <hip/hip_bf16.h>

// Problem dims (fixed by reference): B=64 S=256 F=4 V=50257 H=768 D=512
#define M_TOT 16384   // B*S
#define K_TOT 768     // H
#define N_TOT 512     // D
#define NT 12         // K-chunks of 64
#define NCHUNK 96     // 768/8 fragment chunks of Wt
#define WT_ELEMS ((size_t)N_TOT * K_TOT)

typedef __attribute__((ext_vector_type(8))) __bf16 bf16x8;
typedef __attribute__((ext_vector_type(4))) float f32x4;

static __device__ __forceinline__ ushort f2bf(float x) {
  union { float f; unsigned int u; } v; v.f = x;
  unsigned int r = v.u + 0x7fffu + ((v.u >> 16) & 1u);
  return (ushort)(r >> 16);
}
static __device__ __forceinline__ unsigned pack2(float lo, float hi) {
  return (unsigned)f2bf(lo) | ((unsigned)f2bf(hi) << 16);
}

// ---------------------------------------------------------------------------
// Single FUSED kernel, 8P+4C role-split with the R13 spill fixed:
//   out[16384][512] = mean-gather(E, words) @ W + bias
// 256 blocks (1/CU) x 768 threads (12 waves), ~99KB LDS, __launch_bounds__
// (768,3) -> 170-VGPR budget (R13's failure was VGPR_Count=84: the compiler
// spilled the producer's 24-float4 pipeline to scratch -> 2x slowdown).
// Waves 0-7 = PRODUCERS: R11's contiguous 3KB-row gather (vmcnt = E only).
// Waves 8-11 = CONSUMERS: MFMA + direct-L2 fragment-major Wt B-reads
// (vmcnt = L2 only). This decouples HBM-E waits from L2-B waits (in-order
// vmcnt closed all intra-wave interleaves: R7/R8/R12).
//   P: [Wt?] meta | gather S0 | bar1 | gather S1        | bar2 | exit
//   C: [Wt?] meta | spin Wt-flags | bar1 | GEMM(S0)+st  | bar2 | GEMM(S1)+st
// Wt produced in-kernel by blocks 0..95 (R15); consumers spin pre-bar1 while
// otherwise idle -> zero added latency. Plain stores (R14 write-coalescing).
// Replay-safe: flags re-poisoned -> real wait; identical-value Wt race benign.
// ---------------------------------------------------------------------------
__global__ __launch_bounds__(768, 3) void fused_kernel(
    const int* __restrict__ words, const float* __restrict__ E,
    const float* __restrict__ W, const float* __restrict__ bias,
    ushort* __restrict__ Wt, int* __restrict__ flags,
    float* __restrict__ out) {
  __shared__ ushort A0[32 * 96 * 8];  // 48 KB  [lrow][slot 0..95][8]
  __shared__ ushort A1[32 * 96 * 8];  // 48 KB
  __shared__ int   eoff_l[64][4];
  __shared__ float msk_l[64][4];
  __shared__ float scl_l[64];

  const int t    = threadIdx.x;
  const int lane = t & 63;
  const int w    = t >> 6;   // 0..11
  const int bm   = blockIdx.x;

  // ---- Wt production: block g<96 converts W k-rows [g*8,+8) x all cols ----
  if (bm < NCHUNK) {
    if (t < N_TOT) {
      const int col = t;
      float tmp[8];
#pragma unroll
      for (int e = 0; e < 8; ++e)
        tmp[e] = W[(size_t)(bm * 8 + e) * N_TOT + col];
      ushort4 o0, o1;
      o0.x = f2bf(tmp[0]); o0.y = f2bf(tmp[1]);
      o0.z = f2bf(tmp[2]); o0.w = f2bf(tmp[3]);
      o1.x = f2bf(tmp[4]); o1.y = f2bf(tmp[5]);
      o1.z = f2bf(tmp[6]); o1.w = f2bf(tmp[7]);
      ushort* dst = Wt + ((size_t)bm * N_TOT + col) * 8;
      *reinterpret_cast<ushort4*>(dst)     = o0;
      *reinterpret_cast<ushort4*>(dst + 4) = o1;
    }
    __syncthreads();  // block-uniform branch
    if (t == 0)
      __hip_atomic_store(&flags[bm], 1, __ATOMIC_RELEASE,
                         __HIP_MEMORY_SCOPE_AGENT);
  }

  // ---- metadata for all 64 rows ----
  if (t < 64) {
    const int4 wd =
        *reinterpret_cast<const int4*>(words + (size_t)(bm * 64 + t) * 4);
    const int ids[4] = {wd.x, wd.y, wd.z, wd.w};
    float cnt = 0.f;
#pragma unroll
    for (int f = 0; f < 4; ++f) {
      eoff_l[t][f] = ids[f] * K_TOT;
      const float m = (ids[f] != 0) ? 1.f : 0.f;
      msk_l[t][f] = m;
      cnt += m;
    }
    scl_l[t] = (cnt > 0.f) ? (1.f / cnt) : 0.f;
  }
  __syncthreads();

  if (w < 8) {
    // =============== PRODUCER: wave w owns rows w*4..w*4+3 per sub-tile ====
    const int p4 = w * 4;
    float4 vA[12], vB[12];  // two in-flight rows (static names, rule #20)

#define G_LOAD(vv, S, r)                                                     \
  do {                                                                       \
    const int row_ = (S) * 32 + p4 + (r);                                    \
    _Pragma("unroll") for (int f = 0; f < 4; ++f) {                          \
      const float4* p_ =                                                     \
          reinterpret_cast<const float4*>(E + eoff_l[row_][f]) + lane;       \
      vv[f * 3 + 0] = p_[0];                                                 \
      vv[f * 3 + 1] = p_[64];                                                \
      vv[f * 3 + 2] = p_[128];                                               \
    }                                                                        \
  } while (0)

#define G_MATH(vv, S, r, dstA)                                               \
  do {                                                                       \
    const int row_ = (S) * 32 + p4 + (r);                                    \
    const int lrow_ = p4 + (r);                                              \
    const float km0 = msk_l[row_][0], km1 = msk_l[row_][1];                  \
    const float km2 = msk_l[row_][2], km3 = msk_l[row_][3];                  \
    const float ksc = scl_l[row_];                                           \
    _Pragma("unroll") for (int c = 0; c < 3; ++c) {                          \
      float s[4];                                                            \
      _Pragma("unroll") for (int j = 0; j < 4; ++j)                          \
        s[j] = (vv[0 * 3 + c][j] * km0 + vv[1 * 3 + c][j] * km1 +            \
                vv[2 * 3 + c][j] * km2 + vv[3 * 3 + c][j] * km3) * ksc;      \
      uint2 o_;                                                              \
      o_.x = pack2(s[0], s[1]);                                              \
      o_.y = pack2(s[2], s[3]);                                              \
      const int slot_ = c * 32 + ((lane >> 1) ^ (lrow_ & 7));                \
      *reinterpret_cast<uint2*>(                                             \
          &(dstA)[lrow_ * 768 + slot_ * 8 + (lane & 1) * 4]) = o_;           \
    }                                                                        \
  } while (0)

    // ---- gather S0 -> A0 (depth-2: peak 2 rows = 24 float4 in flight) ----
    G_LOAD(vA, 0, 0);       G_LOAD(vB, 0, 1);
    G_MATH(vA, 0, 0, A0);   G_LOAD(vA, 0, 2);
    G_MATH(vB, 0, 1, A0);   G_LOAD(vB, 0, 3);
    G_MATH(vA, 0, 2, A0);
    G_MATH(vB, 0, 3, A0);
    __syncthreads();  // bar1: A0 ready

    // ---- gather S1 -> A1 (concurrent with consumers' GEMM(S0)) ----
    G_LOAD(vA, 1, 0);       G_LOAD(vB, 1, 1);
    G_MATH(vA, 1, 0, A1);   G_LOAD(vA, 1, 2);
    G_MATH(vB, 1, 1, A1);   G_LOAD(vB, 1, 3);
    G_MATH(vA, 1, 2, A1);
    G_MATH(vB, 1, 3, A1);
    __syncthreads();  // bar2: A1 ready
#undef G_LOAD
#undef G_MATH
  } else {
    // =============== CONSUMER: wave cw covers 32 rows x 128 cols ==========
    const int cw   = w - 8;        // 0..3
    const int ct   = t - 512;      // 0..255
    const int rsel = lane & 15;
    const int ksel = lane >> 4;
    const int colBase = cw * 128 + rsel;
    f32x4 acc[2][8];

#define C_COMPUTE(Asrc, kt)                                                  \
  do {                                                                       \
    _Pragma("unroll") for (int kk = 0; kk < 2; ++kk) {                       \
      const int g = (kt) * 8 + kk * 4 + ksel;                                \
      bf16x8 af[2], bfr[8];                                                  \
      _Pragma("unroll") for (int m = 0; m < 2; ++m) {                        \
        const int r_ = m * 16 + rsel;                                        \
        af[m] = *reinterpret_cast<const bf16x8*>(                            \
            &(Asrc)[r_ * 768 + ((g ^ (r_ & 7))) * 8]);                       \
      }                                                                      \
      _Pragma("unroll") for (int n = 0; n < 8; ++n)                          \
        bfr[n] = *reinterpret_cast<const bf16x8*>(                           \
            &Wt[((size_t)g * N_TOT + colBase + n * 16) * 8]);                \
      __builtin_amdgcn_s_setprio(1);                                         \
      _Pragma("unroll") for (int m = 0; m < 2; ++m)                          \
        _Pragma("unroll") for (int n = 0; n < 8; ++n)                        \
          acc[m][n] = __builtin_amdgcn_mfma_f32_16x16x32_bf16(               \
              af[m], bfr[n], acc[m][n], 0, 0, 0);                            \
      __builtin_amdgcn_s_setprio(0);                                         \
    }                                                                        \
  } while (0)

#define C_EPILOGUE(S)                                                        \
  do {                                                                       \
    const int row0 = bm * 64 + (S) * 32 + (ksel << 2);                       \
    _Pragma("unroll") for (int n = 0; n < 8; ++n) {                          \
      const float bv = bias[colBase + n * 16];                               \
      _Pragma("unroll") for (int m = 0; m < 2; ++m) {                        \
        _Pragma("unroll") for (int j = 0; j < 4; ++j) {                      \
          out[(size_t)(row0 + m * 16 + j) * N_TOT + colBase + n * 16] =      \
              acc[m][n][j] + bv;                                             \
        }                                                                    \
      }                                                                      \
    }                                                                        \
  } while (0)

    // Wt-ready spin while otherwise idle (pre-bar1; flags set ~kernel start)
    if (ct < NCHUNK) {
      while (__hip_atomic_load(&flags[ct], __ATOMIC_ACQUIRE,
                               __HIP_MEMORY_SCOPE_AGENT) != 1) {}
    }
    __syncthreads();  // bar1: A0 ready
#pragma unroll
    for (int m = 0; m < 2; ++m)
#pragma unroll
      for (int n = 0; n < 8; ++n) acc[m][n] = (f32x4){0.f, 0.f, 0.f, 0.f};
#pragma unroll
    for (int kt = 0; kt < NT; ++kt) C_COMPUTE(A0, kt);
    C_EPILOGUE(0);
    __syncthreads();  // bar2: A1 ready
#pragma unroll
    for (int m = 0; m < 2; ++m)
#pragma unroll
      for (int n = 0; n < 8; ++n) acc[m][n] = (f32x4){0.f, 0.f, 0.f, 0.f};
#pragma unroll
    for (int kt = 0; kt < NT; ++kt) C_COMPUTE(A1, kt);
    C_EPILOGUE(1);
#undef C_COMPUTE
#undef C_EPILOGUE
  }
}

// ---------------------------------------------------------------------------
extern "C" void kernel_launch(void* const* d_in, const int* in_sizes, int n_in,
                              void* d_out, int out_size, void* d_ws,
                              size_t ws_size, hipStream_t stream) {
  const int*   words = (const int*)d_in[0];
  const float* E     = (const float*)d_in[1];
  const float* W     = (const float*)d_in[2];
  const float* b     = (const float*)d_in[3];
  float* out = (float*)d_out;

  ushort* Wtws  = (ushort*)d_ws;                       // fragment-major Wt
  int*    flags = (int*)((char*)d_ws + WT_ELEMS * sizeof(ushort));

  hipLaunchKernelGGL(fused_kernel, dim3(M_TOT / 64), dim3(768), 0, stream,
                     words, E, W, b, Wtws, flags, out);
}

// Round 17
// 52.771 us; speedup vs baseline: 2.2450x; 2.2450x over previous
//
#include <hip/hip_runtime.h>
#include <hip/hip_bf16.h>

// Problem dims (fixed by reference): B=64 S=256 F=4 V=50257 H=768 D=512
#define M_TOT 16384   // B*S
#define K_TOT 768     // H
#define N_TOT 512     // D
#define BM 64         // rows per block; 256 blocks = 1/CU
#define NT 12         // K-chunks of 64
#define NCHUNK 96     // 768/8 fragment chunks of Wt
#define WT_ELEMS ((size_t)N_TOT * K_TOT)

typedef __attribute__((ext_vector_type(8))) __bf16 bf16x8;
typedef __attribute__((ext_vector_type(4))) float f32x4;

static __device__ __forceinline__ ushort f2bf(float x) {
  union { float f; unsigned int u; } v; v.f = x;
  unsigned int r = v.u + 0x7fffu + ((v.u >> 16) & 1u);
  return (ushort)(r >> 16);
}
static __device__ __forceinline__ unsigned pack2(float lo, float hi) {
  return (unsigned)f2bf(lo) | ((unsigned)f2bf(hi) << 16);
}

// ---------------------------------------------------------------------------
// Single FUSED kernel (R15 structure — best verified: 52.77us):
//   out[16384][512] = mean-gather(E, words) @ W + bias
// 256 blocks (1/CU, all co-resident) x 512 threads (8 waves), ~97KB LDS.
//
// Final structure after 16 rounds. Key empirical findings baked in:
//  - Contiguous 3KB-row gather (R11): whole E row as 3 back-to-back 1KB
//    wave-loads; depth-2 row pipeline, uniform waves.
//  - Slot-swizzled A-LDS (slot ^= row&7): conflict-free ds ops (R5).
//  - B-fragments read DIRECT from L2-resident fragment-major Wt (R6):
//    no B staging, no per-K barriers; 196MB L2 reads at minimum multiplicity.
//  - PLAIN output stores (R14): nontemporal 4B stores bypassed L2 write
//    coalescing -> 4x WRITE_SIZE amplification (132MB for 33.5MB output).
//  - Wt produced in-kernel by blocks 0..95 + flag spin (R15): saves the
//    separate launch; flags set ~25us before anyone waits.
//  - Overlap mechanisms all empirically closed (R7-R16): in-order vmcnt
//    serializes intra-wave interleave; role-split collapses (compiler
//    minimizes liveness -> serialized gather; VGPR_Count=84 across all
//    attempts); occupancy desync pays more L2 than it hides.
// Floor arithmetic: ~198MB compulsory HBM traffic @ ~4.5-5TB/s sustained
// random-row gather + ~6us serial GEMM + ~4us ramp = 48-52us. This is it.
// ---------------------------------------------------------------------------
__global__ __launch_bounds__(512, 2) void fused_kernel(
    const int* __restrict__ words, const float* __restrict__ E,
    const float* __restrict__ W, const float* __restrict__ bias,
    ushort* __restrict__ Wt, int* __restrict__ flags,
    float* __restrict__ out) {
  __shared__ ushort A_l[BM * 96 * 8];  // [row][slot 0..95][8 elems] = 96 KB
  __shared__ int   eoff_l[BM][4];
  __shared__ float msk_l[BM][4];
  __shared__ float scl_l[BM];

  const int t    = threadIdx.x;
  const int lane = t & 63;
  const int w    = t >> 6;   // 0..7
  const int bm   = blockIdx.x;

  // ---- Wt production: block g<96 converts W[g*8..g*8+8) x all cols ----
  if (bm < NCHUNK) {
    const int col = t;  // 0..511
    float tmp[8];
#pragma unroll
    for (int e = 0; e < 8; ++e)
      tmp[e] = W[(size_t)(bm * 8 + e) * N_TOT + col];
    ushort4 o0, o1;
    o0.x = f2bf(tmp[0]); o0.y = f2bf(tmp[1]);
    o0.z = f2bf(tmp[2]); o0.w = f2bf(tmp[3]);
    o1.x = f2bf(tmp[4]); o1.y = f2bf(tmp[5]);
    o1.z = f2bf(tmp[6]); o1.w = f2bf(tmp[7]);
    ushort* dst = Wt + ((size_t)bm * N_TOT + col) * 8;
    *reinterpret_cast<ushort4*>(dst)     = o0;
    *reinterpret_cast<ushort4*>(dst + 4) = o1;
    __syncthreads();  // block-uniform branch; all slice stores executed
    if (t == 0)
      __hip_atomic_store(&flags[bm], 1, __ATOMIC_RELEASE,
                         __HIP_MEMORY_SCOPE_AGENT);
  }

  // ---- per-row gather metadata (rows bm*64 .. +64) ----
  if (t < BM) {
    const int4 w4 =
        *reinterpret_cast<const int4*>(words + (size_t)(bm * BM + t) * 4);
    const int ids[4] = {w4.x, w4.y, w4.z, w4.w};
    float cnt = 0.f;
#pragma unroll
    for (int f = 0; f < 4; ++f) {
      eoff_l[t][f] = ids[f] * K_TOT;
      const float m = (ids[f] != 0) ? 1.f : 0.f;
      msk_l[t][f] = m;
      cnt += m;
    }
    scl_l[t] = (cnt > 0.f) ? (1.f / cnt) : 0.f;
  }
  __syncthreads();

  // ================= phase 1: gather (wave w owns rows w*8 .. +8) ==========
  const int rbase = w * 8;
  float4 vA[12], vB[12];  // two in-flight rows (static names, rule #20)

#define G_LOAD(vv, r)                                                        \
  do {                                                                       \
    const int row_ = rbase + (r);                                            \
    _Pragma("unroll") for (int f = 0; f < 4; ++f) {                          \
      const float4* p_ =                                                     \
          reinterpret_cast<const float4*>(E + eoff_l[row_][f]) + lane;       \
      vv[f * 3 + 0] = p_[0];                                                 \
      vv[f * 3 + 1] = p_[64];                                                \
      vv[f * 3 + 2] = p_[128];                                               \
    }                                                                        \
  } while (0)

#define G_MATH(vv, r)                                                        \
  do {                                                                       \
    const int row_ = rbase + (r);                                            \
    const float km0 = msk_l[row_][0], km1 = msk_l[row_][1];                  \
    const float km2 = msk_l[row_][2], km3 = msk_l[row_][3];                  \
    const float ksc = scl_l[row_];                                           \
    _Pragma("unroll") for (int c = 0; c < 3; ++c) {                          \
      float s[4];                                                            \
      _Pragma("unroll") for (int j = 0; j < 4; ++j)                          \
        s[j] = (vv[0 * 3 + c][j] * km0 + vv[1 * 3 + c][j] * km1 +            \
                vv[2 * 3 + c][j] * km2 + vv[3 * 3 + c][j] * km3) * ksc;      \
      uint2 o_;                                                              \
      o_.x = pack2(s[0], s[1]);                                              \
      o_.y = pack2(s[2], s[3]);                                              \
      const int slot_ = c * 32 + ((lane >> 1) ^ (r));  /* swizzle ^ row&7 */ \
      *reinterpret_cast<uint2*>(                                             \
          &A_l[row_ * 768 + slot_ * 8 + (lane & 1) * 4]) = o_;               \
    }                                                                        \
  } while (0)

  G_LOAD(vA, 0);  G_LOAD(vB, 1);
  G_MATH(vA, 0);  G_LOAD(vA, 2);
  G_MATH(vB, 1);  G_LOAD(vB, 3);
  G_MATH(vA, 2);  G_LOAD(vA, 4);
  G_MATH(vB, 3);  G_LOAD(vB, 5);
  G_MATH(vA, 4);  G_LOAD(vA, 6);
  G_MATH(vB, 5);  G_LOAD(vB, 7);
  G_MATH(vA, 6);
  G_MATH(vB, 7);
#undef G_LOAD
#undef G_MATH

  // ---- Wt-ready spin (flags were set ~25us ago; normally zero stall) ----
  if (t < NCHUNK) {
    while (__hip_atomic_load(&flags[t], __ATOMIC_ACQUIRE,
                             __HIP_MEMORY_SCOPE_AGENT) != 1) {}
  }
  __syncthreads();  // A tile complete AND Wt ready

  // ================= phase 2: GEMM (wave w: 64 rows x cols [w*64,+64)) =====
  f32x4 acc[4][4];
#pragma unroll
  for (int m = 0; m < 4; ++m)
#pragma unroll
    for (int n = 0; n < 4; ++n) acc[m][n] = (f32x4){0.f, 0.f, 0.f, 0.f};

  const int rsel = lane & 15;   // A row-within-16 / C col-within-16
  const int ksel = lane >> 4;   // 0..3
  const int colBase = w * 64 + rsel;

#pragma unroll
  for (int kt = 0; kt < NT; ++kt) {
#pragma unroll
    for (int kk = 0; kk < 2; ++kk) {
      const int g = kt * 8 + kk * 4 + ksel;  // global 8-elem k-chunk 0..95
      bf16x8 af[4], bfr[4];
#pragma unroll
      for (int m = 0; m < 4; ++m) {
        const int r_ = m * 16 + rsel;
        af[m] = *reinterpret_cast<const bf16x8*>(
            &A_l[r_ * 768 + (g ^ (r_ & 7)) * 8]);
      }
#pragma unroll
      for (int n = 0; n < 4; ++n)
        bfr[n] = *reinterpret_cast<const bf16x8*>(
            &Wt[((size_t)g * N_TOT + colBase + n * 16) * 8]);
      __builtin_amdgcn_s_setprio(1);
#pragma unroll
      for (int m = 0; m < 4; ++m)
#pragma unroll
        for (int n = 0; n < 4; ++n)
          acc[m][n] = __builtin_amdgcn_mfma_f32_16x16x32_bf16(
              af[m], bfr[n], acc[m][n], 0, 0, 0);
      __builtin_amdgcn_s_setprio(0);
    }
  }

  // ---- epilogue: PLAIN stores (L2 write-coalescing; R13/R14 finding) ----
  // C col = lane&15 (+16n), row = (lane>>4)*4 + j (+16m)
  const int row0 = bm * BM + (ksel << 2);
#pragma unroll
  for (int n = 0; n < 4; ++n) {
    const float bv = bias[colBase + n * 16];
#pragma unroll
    for (int m = 0; m < 4; ++m) {
#pragma unroll
      for (int j = 0; j < 4; ++j) {
        out[(size_t)(row0 + m * 16 + j) * N_TOT + colBase + n * 16] =
            acc[m][n][j] + bv;
      }
    }
  }
}

// ---------------------------------------------------------------------------
extern "C" void kernel_launch(void* const* d_in, const int* in_sizes, int n_in,
                              void* d_out, int out_size, void* d_ws,
                              size_t ws_size, hipStream_t stream) {
  const int*   words = (const int*)d_in[0];
  const float* E     = (const float*)d_in[1];
  const float* W     = (const float*)d_in[2];
  const float* b     = (const float*)d_in[3];
  float* out = (float*)d_out;

  ushort* Wtws  = (ushort*)d_ws;                       // fragment-major Wt
  int*    flags = (int*)((char*)d_ws + WT_ELEMS * sizeof(ushort));

  hipLaunchKernelGGL(fused_kernel, dim3(M_TOT / BM), dim3(512), 0, stream,
                     words, E, W, b, Wtws, flags, out);
}